// Round 7
// baseline (153.343 us; speedup 1.0000x reference)
//
#include <hip/hip_runtime.h>
#include <math.h>

namespace {

constexpr int kB = 16, kL = 60, kNC = 80, kNA = 3, kNH = 76, kNW = 76, kNCH = 85;
constexpr int kPlane = kNH * kNW;                 // 5776
constexpr int kQuadsPerPlane = kPlane / 4;        // 1444 (exact)
constexpr int kQuadsPerB = kNA * kQuadsPerPlane;  // 4332
constexpr int kBX = (kQuadsPerB + 255) / 256;     // 17
constexpr int kNPart = kB * kBX;                  // 272
constexpr float kEps = 1e-16f;

// Static partial-sum buffer (no ws_size dependence; fully rewritten every call).
__device__ float g_partials[kNPart];

// st row layout (12 floats = 48 B, 16B-aligned rows):
// [0..3] x1,y1,x2,y2  [4] area  [5] key(bits)  [6] dx [7] dy [8] lw [9] lh [10] sc [11] cls(bits)
__device__ __forceinline__ float sigm(float x) { return 1.0f / (1.0f + expf(-x)); }
// BCE(sigmoid(x), t) = softplus(x) - t*x ; stable softplus:
__device__ __forceinline__ float softplus(float x) {
  return fmaxf(x, 0.0f) + log1pf(expf(-fabsf(x)));
}
__device__ __forceinline__ float anchW(int a) { return a == 0 ? 1.25f : (a == 1 ? 2.0f : 4.125f); }
__device__ __forceinline__ float anchH(int a) { return a == 0 ? 1.625f : (a == 1 ? 3.75f : 2.875f); }

// ---- main: 4 cells/thread, label prep fused. grid = (17, B) x 256 ----
// LDS target reads amortized over 4 IoU evaluations; bulk channels 0..4 as float4.
__global__ __launch_bounds__(256) void main_loss(const float* __restrict__ out,
                                                 const float* __restrict__ labels) {
  const int b = blockIdx.y;
  const int tid = threadIdx.x;
  __shared__ float st[kL][12];
  __shared__ int snv;

  if (tid < 64) {  // wave 0: per-label prep (19 KB total labels -> L2-resident)
    const int l = tid;
    const bool in = l < kL;
    float c0 = 0.f, x = 0.f, y = 0.f, w = 0.f, h = 0.f;
    if (in) {
      const float* p = labels + ((size_t)b * kL + l) * 5;
      c0 = p[0]; x = p[1]; y = p[2]; w = p[3]; h = p[4];
    }
    // n_valid = count of rows with sum>0 ; valid = l < n_valid (prefix, ref quirk)
    const unsigned long long m = __ballot(in && (c0 + x + y + w + h > 0.0f));
    const int nv = __popcll(m);
    if (l == 0) snv = nv;
    if (in) {
      const bool valid = l < nv;
      const float tx = x * (float)kNW, ty = y * (float)kNH;
      const float tw = w * (float)kNW, th = h * (float)kNH;
      const int ti = (int)tx, tj = (int)ty;
      // CIoU of [0,0,tw,th] vs [0,0,aw,ah] (xyxy path), first-max argmax
      const float at0 = atanf(tw / fmaxf(th, kEps));
      float best = -INFINITY;
      int bn = 0;
#pragma unroll
      for (int k = 0; k < kNA; ++k) {
        const float aw = anchW(k), ah = anchH(k);
        const float miw = fminf(tw, aw), mih = fminf(th, ah);
        const float en = ((0.0f < miw) && (0.0f < mih)) ? 1.0f : 0.0f;
        const float ai = miw * mih * en;
        const float au = tw * th + aw * ah - ai;
        const float iou = ai / fmaxf(au, kEps);
        const float dw = tw - aw, dh = th - ah;
        const float rho2 = (dw * dw + dh * dh) * 0.25f;
        const float mw = fmaxf(tw, aw), mh = fmaxf(th, ah);
        const float c2 = mw * mw + mh * mh + kEps;
        const float da = at0 - atanf(aw / ah);
        const float v = (4.0f / (float)(M_PI * M_PI)) * da * da;
        const float alpha = v / fmaxf(1.0f - iou + v, kEps);
        const float ciou = iou - (rho2 / c2 + v * alpha);
        if (ciou > best) { best = ciou; bn = k; }
      }
      st[l][0] = tx - tw * 0.5f; st[l][1] = ty - th * 0.5f;
      st[l][2] = tx + tw * 0.5f; st[l][3] = ty + th * 0.5f;
      st[l][4] = tw * th;
      st[l][5] = __int_as_float(valid ? ((bn * kNH + tj) * kNW + ti) : -1);
      st[l][6] = tx - floorf(tx);
      st[l][7] = ty - floorf(ty);
      st[l][8] = logf(tw / anchW(bn) + kEps);
      st[l][9] = logf(th / anchH(bn) + kEps);
      st[l][10] = sqrtf(2.0f - tw * th * (1.0f / (float)(kNW * kNH)));
      st[l][11] = __int_as_float((int)c0);
    }
  }
  __syncthreads();

  const int qid = blockIdx.x * 256 + tid;
  const bool active = qid < kQuadsPerB;
  int a = 0, r4 = 0;
  if (active) { a = qid / kQuadsPerPlane; r4 = (qid - a * kQuadsPerPlane) * 4; }
  const int cbase = a * kPlane + r4;  // cell index of sub-cell 0 (== key encoding)

  float xc[5][4];                  // channel x sub-cell (all indices compile-time)
  float px1[4], px2[4], py1[4], py2[4], ap[4];
  int winner[4] = {-1, -1, -1, -1};
  unsigned flags = 0;
  float acc = 0.0f;

  if (active) {
    const float* base = out + ((size_t)(b * kNA + a) * kNCH) * kPlane + r4;
#pragma unroll
    for (int ch = 0; ch < 5; ++ch) {
      const float4 v = *reinterpret_cast<const float4*>(base + (size_t)ch * kPlane);
      xc[ch][0] = v.x; xc[ch][1] = v.y; xc[ch][2] = v.z; xc[ch][3] = v.w;
    }
    const float aw = anchW(a), ah = anchH(a);
#pragma unroll
    for (int k = 0; k < 4; ++k) {
      const int r = r4 + k;
      const int j = r / kNW, i = r - j * kNW;
      const float px = sigm(xc[0][k]) + (float)i;
      const float py = sigm(xc[1][k]) + (float)j;
      const float pw = expf(xc[2][k]) * aw;
      const float ph = expf(xc[3][k]) * ah;
      px1[k] = px - 0.5f * pw; px2[k] = px + 0.5f * pw;
      py1[k] = py - 0.5f * ph; py2[k] = py + 0.5f * ph;
      ap[k] = pw * ph;
    }
    const int nv = snv;
#pragma unroll 4
    for (int t = 0; t < nv; ++t) {
      const float4 bx = *reinterpret_cast<const float4*>(&st[t][0]);  // broadcast b128
      const float2 ak = *reinterpret_cast<const float2*>(&st[t][4]);  // broadcast b64
      const int key = __float_as_int(ak.y);
#pragma unroll
      for (int k = 0; k < 4; ++k) {
        const float tlx = fmaxf(px1[k], bx.x), tly = fmaxf(py1[k], bx.y);
        const float brx = fminf(px2[k], bx.z), bry = fminf(py2[k], bx.w);
        const bool ok = (tlx < brx) && (tly < bry);
        const float ai = ok ? (brx - tlx) * (bry - tly) : 0.0f;
        if (ai + ai > ap[k] + ak.x - ai) flags |= (1u << k);  // iou > 0.5, division-free
        if (key == cbase + k) winner[k] = t;                  // last valid label wins
      }
    }
#pragma unroll
    for (int k = 0; k < 4; ++k) {
      const float sp4 = softplus(xc[4][k]);
      if (winner[k] >= 0) {
        acc += sp4 - xc[4][k];  // obj (tobj=1)
        const float sc = st[winner[k]][10];
        const float w2 = sc * sc;
        acc += (softplus(xc[0][k]) - st[winner[k]][6] * xc[0][k] +
                softplus(xc[1][k]) - st[winner[k]][7] * xc[1][k]) * w2;  // xy
        const float d2 = xc[2][k] - st[winner[k]][8], d3 = xc[3][k] - st[winner[k]][9];
        acc += 0.5f * w2 * (d2 * d2 + d3 * d3);  // wh
      } else if (!((flags >> k) & 1u)) {
        acc += sp4;  // obj_mask=1 (best_iou<=0.5), tobj=0
      }
    }
  }

  // ---- wave-cooperative class loss for winner cells (<=960 total) ----
  // Ballots uniform across the wave (outside any divergent branch).
  const int lane = tid & 63;
#pragma unroll
  for (int k = 0; k < 4; ++k) {
    unsigned long long pend = __ballot(winner[k] >= 0);
    while (pend) {
      const int src = (int)(__ffsll(pend) - 1);
      pend &= pend - 1;
      const int wc = __shfl(cbase + k, src);
      const int wt = __shfl(winner[k], src);
      const int cls = __float_as_int(st[wt][11]);  // uniform LDS addr -> broadcast
      const unsigned wa = (unsigned)wc / (unsigned)kPlane;
      const unsigned wr = (unsigned)wc - wa * (unsigned)kPlane;
      const float* wb = out + ((size_t)(b * kNA + (int)wa) * kNCH + 5) * kPlane + wr;
      const float v0 = wb[(size_t)lane * kPlane];
      float s = softplus(v0) - (lane == cls ? v0 : 0.0f);
      if (lane < kNC - 64) {  // lanes 0..15 also cover classes 64..79
        const float v1 = wb[(size_t)(lane + 64) * kPlane];
        s += softplus(v1) - (lane + 64 == cls ? v1 : 0.0f);
      }
#pragma unroll
      for (int off = 32; off > 0; off >>= 1) s += __shfl_down(s, off);
      if (lane == 0) acc += s;
    }
  }

  // deterministic block reduction
#pragma unroll
  for (int off = 32; off > 0; off >>= 1) acc += __shfl_down(acc, off);
  __shared__ float sred[4];
  if ((tid & 63) == 0) sred[tid >> 6] = acc;
  __syncthreads();
  if (tid == 0) g_partials[b * kBX + blockIdx.x] = sred[0] + sred[1] + sred[2] + sred[3];
}

// ---------------- final deterministic reduce ----------------
__global__ void finalize(float* __restrict__ outp) {
  const int tid = threadIdx.x;
  double acc = 0.0;
  for (int idx = tid; idx < kNPart; idx += 256) acc += (double)g_partials[idx];
  __shared__ double s[256];
  s[tid] = acc;
  __syncthreads();
  for (int off = 128; off > 0; off >>= 1) {
    if (tid < off) s[tid] += s[tid + off];
    __syncthreads();
  }
  if (tid == 0) outp[0] = (float)(s[0] / (double)kB);
}

}  // namespace

extern "C" void kernel_launch(void* const* d_in, const int* in_sizes, int n_in,
                              void* d_out, int out_size, void* d_ws, size_t ws_size,
                              hipStream_t stream) {
  const float* output = (const float*)d_in[0];  // (B, NA*85, 76, 76) f32
  const float* target = (const float*)d_in[1];  // (B, L, 5) f32
  float* outp = (float*)d_out;                  // scalar f32
  (void)d_ws; (void)ws_size;                    // workspace unused (static g_partials)

  main_loss<<<dim3(kBX, kB), 256, 0, stream>>>(output, target);
  finalize<<<1, 256, 0, stream>>>(outp);
}

// Round 11
// 143.064 us; speedup vs baseline: 1.0718x; 1.0718x over previous
//
#include <hip/hip_runtime.h>
#include <math.h>

namespace {

constexpr int kB = 16, kL = 60, kNC = 80, kNA = 3, kNH = 76, kNW = 76, kNCH = 85;
constexpr int kPlane = kNH * kNW;              // 5776
constexpr int kCellsPerB = kNA * kPlane;       // 17328
constexpr int kBX = (kCellsPerB + 255) / 256;  // 68
constexpr int kNPart = kB * kBX;               // 1088
constexpr float kEps = 1e-16f;

// 32 B-aligned so one s_load_dwordx8 fetches a whole target box.
struct __align__(32) BoxT { float x1, y1, x2, y2, area; int key; int p0, p1; };
struct __align__(32) RegT { float dx, dy, lw, lh, sc; int cls; int p0, p1; };

// Static buffers (no ws_size dependence; fully rewritten every call).
__device__ BoxT g_boxes[kB][kL];
__device__ RegT g_regr[kB][kL];
__device__ int g_nv[kB];
__device__ float g_partials[kNPart];

__device__ __forceinline__ float sigm(float x) { return 1.0f / (1.0f + expf(-x)); }
// BCE(sigmoid(x), t) = softplus(x) - t*x ; stable softplus:
__device__ __forceinline__ float softplus(float x) {
  return fmaxf(x, 0.0f) + log1pf(expf(-fabsf(x)));
}
__device__ __forceinline__ float anchW(int a) { return a == 0 ? 1.25f : (a == 1 ? 2.0f : 4.125f); }
__device__ __forceinline__ float anchH(int a) { return a == 0 ? 1.625f : (a == 1 ? 3.75f : 2.875f); }

// ---------------- prep: per-label targets -> global (16 blocks x 64 = one wave) -----------
__global__ void prep_labels(const float* __restrict__ labels) {
  const int b = blockIdx.x;
  const int l = threadIdx.x;
  const bool in = l < kL;
  float c0 = 0.f, x = 0.f, y = 0.f, w = 0.f, h = 0.f;
  if (in) {
    const float* p = labels + ((size_t)b * kL + l) * 5;
    c0 = p[0]; x = p[1]; y = p[2]; w = p[3]; h = p[4];
  }
  // n_valid = count of rows with sum>0 ; valid = l < n_valid (prefix, mirrors ref quirk)
  const unsigned long long m = __ballot(in && (c0 + x + y + w + h > 0.0f));
  const int nv = __popcll(m);
  if (l == 0) g_nv[b] = nv;
  if (!in) return;
  const bool valid = l < nv;

  const float tx = x * (float)kNW, ty = y * (float)kNH;
  const float tw = w * (float)kNW, th = h * (float)kNH;
  const int ti = (int)tx, tj = (int)ty;

  // CIoU of [0,0,tw,th] vs [0,0,aw,ah] (xyxy path of pairwise_iou), first-max argmax
  const float at0 = atanf(tw / fmaxf(th, kEps));
  float best = -INFINITY;
  int bn = 0;
#pragma unroll
  for (int k = 0; k < kNA; ++k) {
    const float aw = anchW(k), ah = anchH(k);
    const float miw = fminf(tw, aw), mih = fminf(th, ah);
    const float en = ((0.0f < miw) && (0.0f < mih)) ? 1.0f : 0.0f;
    const float ai = miw * mih * en;
    const float au = tw * th + aw * ah - ai;
    const float iou = ai / fmaxf(au, kEps);
    const float dw = tw - aw, dh = th - ah;
    const float rho2 = (dw * dw + dh * dh) * 0.25f;
    const float mw = fmaxf(tw, aw), mh = fmaxf(th, ah);
    const float c2 = mw * mw + mh * mh + kEps;
    const float da = at0 - atanf(aw / ah);
    const float v = (4.0f / (float)(M_PI * M_PI)) * da * da;
    const float alpha = v / fmaxf(1.0f - iou + v, kEps);
    const float ciou = iou - (rho2 / c2 + v * alpha);
    if (ciou > best) { best = ciou; bn = k; }
  }

  BoxT bx;
  bx.x1 = tx - tw * 0.5f; bx.y1 = ty - th * 0.5f;
  bx.x2 = tx + tw * 0.5f; bx.y2 = ty + th * 0.5f;
  bx.area = tw * th;
  bx.key = valid ? ((bn * kNH + tj) * kNW + ti) : -1;
  bx.p0 = 0; bx.p1 = 0;
  g_boxes[b][l] = bx;

  RegT rg;
  rg.dx = tx - floorf(tx);
  rg.dy = ty - floorf(ty);
  rg.lw = logf(tw / anchW(bn) + kEps);
  rg.lh = logf(th / anchH(bn) + kEps);
  rg.sc = sqrtf(2.0f - tw * th * (1.0f / (float)(kNW * kNH)));
  rg.cls = (int)c0;
  rg.p0 = 0; rg.p1 = 0;
  g_regr[b][l] = rg;
}

// ---- main: per-cell loss, targets via uniform (scalar) loads. grid = (68, B) x 256 ----
// t-loop is in uniform control flow with a uniform address -> s_load into SGPRs;
// no LDS on the hot path. Class channels touched only at the <=960 winner cells.
__global__ __launch_bounds__(256) void main_loss(const float* __restrict__ out,
                                                 float* __restrict__ partials_unused) {
  const int b = blockIdx.y;
  const int tid = threadIdx.x;
  const int c = blockIdx.x * 256 + tid;
  const bool active = c < kCellsPerB;
  const int cs = active ? c : 0;    // clamped for safe addressing on tail lanes
  const int ckey = active ? c : -9; // never matches any key (keys are -1 or >=0)

  const unsigned a = (unsigned)cs / (unsigned)kPlane;
  const unsigned r = (unsigned)cs - a * (unsigned)kPlane;
  const unsigned j = r / (unsigned)kNW;
  const unsigned i = r - j * (unsigned)kNW;
  const float* base = out + ((size_t)(b * kNA + (int)a) * kNCH) * kPlane + r;
  const float x0 = base[0];
  const float x1 = base[(size_t)kPlane];
  const float x2 = base[(size_t)2 * kPlane];
  const float x3 = base[(size_t)3 * kPlane];
  const float x4 = base[(size_t)4 * kPlane];

  // pred box (cx,cy,w,h) -> corners
  const float px = sigm(x0) + (float)i;
  const float py = sigm(x1) + (float)j;
  const float pw = expf(x2) * anchW((int)a);
  const float ph = expf(x3) * anchH((int)a);
  const float px1 = px - 0.5f * pw, px2 = px + 0.5f * pw;
  const float py1 = py - 0.5f * ph, py2 = py + 0.5f * ph;
  const float ap = pw * ph;

  // flag = (max IoU over valid targets) > 0.5 ; winner = last label scattering to this cell
  bool flag = false;
  int winner = -1;
  const int nv = g_nv[b];                      // uniform -> s_load
  const BoxT* __restrict__ bp = g_boxes[b];    // uniform base
#pragma unroll 4
  for (int t = 0; t < nv; ++t) {
    const BoxT bx = bp[t];                     // uniform addr -> s_load_dwordx8 (SGPRs)
    const float tlx = fmaxf(px1, bx.x1), tly = fmaxf(py1, bx.y1);
    const float brx = fminf(px2, bx.x2), bry = fminf(py2, bx.y2);
    const bool ok = (tlx < brx) && (tly < bry);
    const float ai = ok ? (brx - tlx) * (bry - tly) : 0.0f;
    flag = flag || (ai + ai > ap + bx.area - ai);  // iou > 0.5 (division-free, exact)
    if (bx.key == ckey) winner = t;                // last valid label wins collisions
  }

  float acc = 0.0f;
  if (active) {
    const float sp4 = softplus(x4);
    if (winner >= 0) {
      // scattered cell: obj_mask=1, tobj=1, plus xy/wh terms (cls handled below)
      const RegT rg = g_regr[b][winner];  // per-lane gather, <=960 total
      acc += sp4 - x4;
      const float w2 = rg.sc * rg.sc;
      acc += (softplus(x0) - rg.dx * x0 + softplus(x1) - rg.dy * x1) * w2;  // xy
      const float d2 = x2 - rg.lw, d3 = x3 - rg.lh;
      acc += 0.5f * w2 * (d2 * d2 + d3 * d3);                               // wh
    } else if (!flag) {
      acc += sp4;  // obj_mask=1 (best_iou<=0.5 or no valid targets), tobj=0
    }
    // else: obj_mask=0 -> contributes 0
  }

  // ---- wave-cooperative class loss for winner cells (<=960 total, ~0.9/wave) ----
  // Ballot sits in uniform control flow; 64 lanes cover the 80 class logits of one
  // winner cell (lane k -> classes k and k+64), fusing the -x_cls term.
  {
    const int lane = tid & 63;
    unsigned long long pend = __ballot(winner >= 0);
    while (pend) {
      const int src = (int)(__ffsll(pend) - 1);
      pend &= pend - 1;
      const int wc = __shfl(c, src);
      const int wt = __shfl(winner, src);
      const int cls = g_regr[b][wt].cls;  // same addr across wave -> 1 line
      const unsigned wa = (unsigned)wc / (unsigned)kPlane;
      const unsigned wr = (unsigned)wc - wa * (unsigned)kPlane;
      const float* wb = out + ((size_t)(b * kNA + (int)wa) * kNCH + 5) * kPlane + wr;
      const float v0 = wb[(size_t)lane * kPlane];
      float s = softplus(v0) - (lane == cls ? v0 : 0.0f);
      if (lane < kNC - 64) {  // lanes 0..15 also cover classes 64..79
        const float v1 = wb[(size_t)(lane + 64) * kPlane];
        s += softplus(v1) - (lane + 64 == cls ? v1 : 0.0f);
      }
#pragma unroll
      for (int off = 32; off > 0; off >>= 1) s += __shfl_down(s, off);
      if (lane == 0) acc += s;
    }
  }

  // deterministic block reduction (wave shfl + tiny LDS)
#pragma unroll
  for (int off = 32; off > 0; off >>= 1) acc += __shfl_down(acc, off);
  __shared__ float sred[4];
  if ((tid & 63) == 0) sred[tid >> 6] = acc;
  __syncthreads();
  if (tid == 0) g_partials[b * kBX + blockIdx.x] = sred[0] + sred[1] + sred[2] + sred[3];
}

// ---------------- final deterministic reduce ----------------
__global__ void finalize(float* __restrict__ outp) {
  const int tid = threadIdx.x;
  double acc = 0.0;
  for (int idx = tid; idx < kNPart; idx += 256) acc += (double)g_partials[idx];
  __shared__ double s[256];
  s[tid] = acc;
  __syncthreads();
  for (int off = 128; off > 0; off >>= 1) {
    if (tid < off) s[tid] += s[tid + off];
    __syncthreads();
  }
  if (tid == 0) outp[0] = (float)(s[0] / (double)kB);
}

}  // namespace

extern "C" void kernel_launch(void* const* d_in, const int* in_sizes, int n_in,
                              void* d_out, int out_size, void* d_ws, size_t ws_size,
                              hipStream_t stream) {
  const float* output = (const float*)d_in[0];  // (B, NA*85, 76, 76) f32
  const float* target = (const float*)d_in[1];  // (B, L, 5) f32
  float* outp = (float*)d_out;                  // scalar f32
  (void)d_ws; (void)ws_size;                    // workspace unused (static buffers)

  prep_labels<<<kB, 64, 0, stream>>>(target);
  main_loss<<<dim3(kBX, kB), 256, 0, stream>>>(output, nullptr);
  finalize<<<1, 256, 0, stream>>>(outp);
}